// Round 5
// baseline (158.227 us; speedup 1.0000x reference)
//
#include <hip/hip_runtime.h>
#include <hip/hip_bf16.h>
#include <stdint.h>

#define N_DIM 1024
#define DEPTH 2
#define ABCD_TOTAL 4092   // 2*(1024+512+...+2)

typedef __attribute__((ext_vector_type(8))) short short8;   // 8 bf16 (4 VGPRs)
typedef __attribute__((ext_vector_type(4))) float floatx4;  // MFMA accumulator
typedef __attribute__((ext_vector_type(4))) float f4;       // {re0,im0,re1,im1}

__device__ __forceinline__ f4 cmul(float cr, float ci, f4 v) {
    f4 r;
    r[0] = cr * v[0] - ci * v[1];
    r[1] = cr * v[1] + ci * v[0];
    r[2] = cr * v[2] - ci * v[3];
    r[3] = cr * v[3] + ci * v[2];
    return r;
}

// ---------------------------------------------------------------------------
// Kernel 1 (fused): blocks [0,512) build W; blocks [512, 512+8192) cast x.
// Wave-synchronous stages (perm s<=7, diag pairs (1,2)..(7,8)) use only
// __builtin_amdgcn_wave_barrier(); full __syncthreads at cross-wave stages.
// ---------------------------------------------------------------------------
__global__ __launch_bounds__(256) void build_and_cast(
    const float* __restrict__ perm_logit,  // (2,3)
    const float* __restrict__ abcd,        // (2,4092,2)
    const float* __restrict__ x,           // (16384,1024)
    __hip_bfloat16* __restrict__ S,        // (1024 i, 1024 j)
    __hip_bfloat16* __restrict__ xb)       // (16384,1024) bf16
{
    const int bx  = blockIdx.x;
    const int tid = threadIdx.x;
    __shared__ f4 h[2][N_DIM];  // ping-pong interleaved buffers, 32 KB

    if (bx >= 512) {  // ---- cast part ----
        const int cb = bx - 512;
        const size_t i = ((size_t)cb * 256 + tid) * 8;
        float4 v0 = *(const float4*)(x + i);
        float4 v1 = *(const float4*)(x + i + 4);
        union { __hip_bfloat16 e[8]; int4 v; } u;
        u.e[0] = __float2bfloat16(v0.x); u.e[1] = __float2bfloat16(v0.y);
        u.e[2] = __float2bfloat16(v0.z); u.e[3] = __float2bfloat16(v0.w);
        u.e[4] = __float2bfloat16(v1.x); u.e[5] = __float2bfloat16(v1.y);
        u.e[6] = __float2bfloat16(v1.z); u.e[7] = __float2bfloat16(v1.w);
        *(int4*)(xb + i) = u.v;
        return;
    }

    // ---- build part ----
    const int row0 = bx * 2;
    const f4 zz = {0.0f, 0.0f, 0.0f, 0.0f};
    for (int j = tid; j < N_DIM; j += 256) { h[0][j] = zz; h[1][j] = zz; }
    __syncthreads();
    if (tid == 0) {
        f4 e0 = {1.0f, 0.0f, 0.0f, 0.0f};
        f4 e1 = {0.0f, 0.0f, 1.0f, 0.0f};
        h[0][row0]     = e0;
        h[0][row0 + 1] = e1;
    }
    __syncthreads();

    int cur = 0;
    for (int d = 0; d < DEPTH; ++d) {
        const float p0 = 1.0f / (1.0f + expf(-perm_logit[d * 3 + 0]));
        const float p1 = 1.0f / (1.0f + expf(-perm_logit[d * 3 + 1]));
        const float p2 = 1.0f / (1.0f + expf(-perm_logit[d * 3 + 2]));

        // ---- perm factors, m = 4 .. 1024 (ascending) ----
#pragma unroll
        for (int s = 2; s <= 10; ++s) {
            if (s >= 8) __syncthreads();             // cross-wave mixing starts
            else        __builtin_amdgcn_wave_barrier();
            const int half = 1 << (s - 1), hq = half >> 1;
            const int cnt   = (d == 0) ? half : 512;
            const int pbase = (d == 0) ? ((row0 >> s) << (s - 1)) : 0;
            const f4* __restrict__ in = h[cur];
            f4* __restrict__ out      = h[cur ^ 1];
            for (int tt = tid; tt < cnt; tt += 256) {
                const int t    = pbase + tt;
                const int blk  = t >> (s - 1);
                const int r    = t & (half - 1);
                const int base = blk << s;
                int q1, q2; float pc;
                if (r < hq) { q1 = r;           q2 = half - 1 - r;   pc = p1; }
                else        { int r2 = r - hq;  q1 = half + r2;
                              q2 = 2 * half - 1 - r2;                pc = p2; }
                const int src1 = (q1 < half) ? 2 * q1 : 2 * (q1 - half) + 1;
                const int src2 = (q2 < half) ? 2 * q2 : 2 * (q2 - half) + 1;
                f4 b1 = in[base + q1], a1 = in[base + src1];
                f4 b2 = in[base + q2], a2 = in[base + src2];
                f4 s1a = b1 + p0 * (a1 - b1);
                f4 s1b = b2 + p0 * (a2 - b2);
                out[base + q1] = s1a + pc * (s1b - s1a);
                out[base + q2] = s1b + pc * (s1a - s1b);
            }
            cur ^= 1;
        }
        __syncthreads();  // perm s=10 output is block-wide

        // ---- diag factors fused in pairs: (1,2)..(9,10) ----
        const float* __restrict__ abd = abcd + (size_t)d * (ABCD_TOTAL * 2);
#pragma unroll
        for (int s = 1; s <= 9; s += 2) {
            if (s == 9) __syncthreads();             // (9,10) mixes across waves
            else        __builtin_amdgcn_wave_barrier();
            const int hh = 1 << (s - 1);
            const float* __restrict__ ab1 = abd + (size_t)(4096 - 8 * hh) * 2;
            const float* __restrict__ ab2 = abd + (size_t)(4096 - 16 * hh) * 2;
            const f4* __restrict__ in = h[cur];
            f4* __restrict__ out      = h[cur ^ 1];
            {
                const int g     = tid;
                const int k     = g & (hh - 1);
                const int base2 = (g >> (s - 1)) << (s + 1);
                f4 x0 = in[base2 + k];
                f4 x1 = in[base2 + k + hh];
                f4 x2 = in[base2 + k + 2 * hh];
                f4 x3 = in[base2 + k + 3 * hh];
                float2 A = *(const float2*)(ab1 + 2 * (size_t)k);
                float2 B = *(const float2*)(ab1 + 2 * (size_t)(hh + k));
                float2 C = *(const float2*)(ab1 + 2 * (size_t)(2 * hh + k));
                float2 D = *(const float2*)(ab1 + 2 * (size_t)(3 * hh + k));
                f4 y0 = cmul(A.x, A.y, x0) + cmul(B.x, B.y, x1);
                f4 y1 = cmul(C.x, C.y, x0) + cmul(D.x, D.y, x1);
                f4 y2 = cmul(A.x, A.y, x2) + cmul(B.x, B.y, x3);
                f4 y3 = cmul(C.x, C.y, x2) + cmul(D.x, D.y, x3);
                float2 A2 = *(const float2*)(ab2 + 2 * (size_t)k);
                float2 B2 = *(const float2*)(ab2 + 2 * (size_t)(2 * hh + k));
                float2 C2 = *(const float2*)(ab2 + 2 * (size_t)(4 * hh + k));
                float2 D2 = *(const float2*)(ab2 + 2 * (size_t)(6 * hh + k));
                float2 A3 = *(const float2*)(ab2 + 2 * (size_t)(hh + k));
                float2 B3 = *(const float2*)(ab2 + 2 * (size_t)(3 * hh + k));
                float2 C3 = *(const float2*)(ab2 + 2 * (size_t)(5 * hh + k));
                float2 D3 = *(const float2*)(ab2 + 2 * (size_t)(7 * hh + k));
                out[base2 + k]          = cmul(A2.x, A2.y, y0) + cmul(B2.x, B2.y, y2);
                out[base2 + k + 2 * hh] = cmul(C2.x, C2.y, y0) + cmul(D2.x, D2.y, y2);
                out[base2 + k + hh]     = cmul(A3.x, A3.y, y1) + cmul(B3.x, B3.y, y3);
                out[base2 + k + 3 * hh] = cmul(C3.x, C3.y, y1) + cmul(D3.x, D3.y, y3);
            }
            cur ^= 1;
        }
        __syncthreads();  // (9,10) output is block-wide
    }

    for (int j = tid; j < N_DIM; j += 256) {
        f4 v = h[cur][j];
        S[(size_t)row0 * N_DIM + j]       = __float2bfloat16(v[0]);
        S[(size_t)(row0 + 1) * N_DIM + j] = __float2bfloat16(v[2]);
    }
}

// ---------------------------------------------------------------------------
// Kernel 2: transpose S (i-major) -> Wt (j-major, contiguous k) via LDS tiles.
// ---------------------------------------------------------------------------
__global__ __launch_bounds__(256) void transpose_w(
    const __hip_bfloat16* __restrict__ S, __hip_bfloat16* __restrict__ Wt)
{
    const int i0 = (blockIdx.x & 15) * 64;
    const int j0 = (blockIdx.x >> 4) * 64;
    __shared__ __hip_bfloat16 tile[64][72];
    const int r  = threadIdx.x >> 2;
    const int c0 = (threadIdx.x & 3) * 16;
    *(short8*)&tile[r][c0]     = *(const short8*)(S + (size_t)(i0 + r) * N_DIM + j0 + c0);
    *(short8*)&tile[r][c0 + 8] = *(const short8*)(S + (size_t)(i0 + r) * N_DIM + j0 + c0 + 8);
    __syncthreads();
    union { __hip_bfloat16 e[8]; short8 v; } o1, o2;
#pragma unroll
    for (int k = 0; k < 8; ++k) { o1.e[k] = tile[c0 + k][r]; o2.e[k] = tile[c0 + 8 + k][r]; }
    *(short8*)(Wt + (size_t)(j0 + r) * N_DIM + i0 + c0)     = o1.v;
    *(short8*)(Wt + (size_t)(j0 + r) * N_DIM + i0 + c0 + 8) = o2.v;
}

// ---------------------------------------------------------------------------
// Kernel 3: out = x(16384x1024 bf16) @ W + bias, fp32 out.
// 128x128 tile, BK=128 (8 K-iters -> 16 barrier drains, was 32),
// LDS 64 KB -> 2 blocks/CU (grid 1024 = 2 clean rounds).
// Row = 256 B = 16 chunks of 16 B; global chunk c stored at LDS slot
// c ^ (row&15) (swizzle on the GLOBAL side; gl_lds LDS side stays
// lane-contiguous). Frag read slot = (ks*4+lq) ^ lrow -> <=4 lanes/slot.
// ---------------------------------------------------------------------------
#define BM 128
#define BN 128
#define BK 128

__device__ __forceinline__ void gl_lds16(const void* g, void* l) {
    __builtin_amdgcn_global_load_lds(
        (const __attribute__((address_space(1))) uint32_t*)g,
        (__attribute__((address_space(3))) uint32_t*)l, 16, 0, 0);
}

__global__ __launch_bounds__(256, 2) void gemm_bt(
    const __hip_bfloat16* __restrict__ A,   // (16384, 1024)
    const __hip_bfloat16* __restrict__ Bt,  // (1024 n, 1024 k)
    const float* __restrict__ bias,         // (1024)
    float* __restrict__ C)                  // (16384, 1024)
{
    const int tid = threadIdx.x;
    const int bx  = blockIdx.x;
    const int xcd = bx & 7;
    const int loc = bx >> 3;
    const int m0  = (xcd * 16 + (loc >> 3)) * BM;
    const int n0  = (loc & 7) * BN;

    __shared__ __hip_bfloat16 sA[BM * BK];  // 32 KB
    __shared__ __hip_bfloat16 sB[BN * BK];  // 32 KB

    const int lane = tid & 63;
    const int wm   = ((tid >> 6) & 1) * 64;
    const int wn   = ((tid >> 6) >> 1) * 64;
    const int lrow = lane & 15;
    const int lq   = lane >> 4;

    // staging: granule g = tid + i*256, i<8; row = g>>4 = (tid>>4) + i*16,
    // LDS slot = g&15 = tid&15, global chunk cs = (tid&15) ^ ((tid>>4)&15)
    // (row&15 == (tid>>4)&15 since i*16 == 0 mod 16).
    const int r1 = tid >> 4;
    const int cs = (tid & 15) ^ (r1 & 15);

    floatx4 acc[4][4] = {};

    for (int kt = 0; kt < 8; ++kt) {
        const int k0 = kt * BK;
#pragma unroll
        for (int i = 0; i < 8; ++i)
            gl_lds16(A + (size_t)(m0 + r1 + i * 16) * N_DIM + k0 + cs * 8,
                     (char*)sA + (tid + i * 256) * 16);
#pragma unroll
        for (int i = 0; i < 8; ++i)
            gl_lds16(Bt + (size_t)(n0 + r1 + i * 16) * N_DIM + k0 + cs * 8,
                     (char*)sB + (tid + i * 256) * 16);
        __syncthreads();

#pragma unroll
        for (int ks = 0; ks < 4; ++ks) {
            short8 af[4], bf[4];
            const int slot = (ks * 4 + lq) ^ lrow;
#pragma unroll
            for (int i = 0; i < 4; ++i) {
                af[i] = *(const short8*)((const char*)sA + (wm + i * 16 + lrow) * 256 + slot * 16);
                bf[i] = *(const short8*)((const char*)sB + (wn + i * 16 + lrow) * 256 + slot * 16);
            }
#pragma unroll
            for (int i = 0; i < 4; ++i)
#pragma unroll
                for (int j = 0; j < 4; ++j)
                    acc[i][j] = __builtin_amdgcn_mfma_f32_16x16x32_bf16(
                        af[i], bf[j], acc[i][j], 0, 0, 0);
        }
        __syncthreads();
    }

#pragma unroll
    for (int j = 0; j < 4; ++j) {
        const int gn = n0 + wn + j * 16 + lrow;
        const float bv = bias[gn];
#pragma unroll
        for (int i = 0; i < 4; ++i) {
            const int gm = m0 + wm + i * 16 + lq * 4;
#pragma unroll
            for (int r = 0; r < 4; ++r)
                C[(size_t)(gm + r) * N_DIM + gn] = acc[i][j][r] + bv;
        }
    }
}

// ---------------------------------------------------------------------------
extern "C" void kernel_launch(void* const* d_in, const int* in_sizes, int n_in,
                              void* d_out, int out_size, void* d_ws, size_t ws_size,
                              hipStream_t stream) {
    const float* x          = (const float*)d_in[0];
    const float* perm_logit = (const float*)d_in[1];
    const float* abcd       = (const float*)d_in[2];
    const float* bias       = (const float*)d_in[3];
    float* out              = (float*)d_out;

    // S (2 MB) lives in d_out scratch space (gemm overwrites d_out afterward).
    __hip_bfloat16* S  = (__hip_bfloat16*)d_out;
    __hip_bfloat16* Wt = (__hip_bfloat16*)d_ws;                      // 2 MB
    __hip_bfloat16* xb = (__hip_bfloat16*)((char*)d_ws + (1 << 21)); // 32 MB

    build_and_cast<<<dim3(512 + 8192), dim3(256), 0, stream>>>(perm_logit, abcd, x, S, xb);
    transpose_w<<<dim3(256), dim3(256), 0, stream>>>(S, Wt);
    gemm_bt<<<dim3(1024), dim3(256), 0, stream>>>(xb, Wt, bias, out);
}